// Round 12
// baseline (156.891 us; speedup 1.0000x reference)
//
#include <hip/hip_runtime.h>
#include <stdint.h>

// ---------------------------------------------------------------------------
// MultiExpertMultiHeadAttention  (B=8,S=512,D=256,E=8,H=4,DH=64)
// Round 12: single change vs R11 — out-GEMM stores go through L2 (plain
// stores) instead of nontemporal HBM-bypass. Theory: NT bypass defeats L2
// write aggregation; fill kernels prove normal-store path hits 6.8 TB/s.
// ---------------------------------------------------------------------------

typedef __bf16 bf16x8 __attribute__((ext_vector_type(8)));
typedef float f32x4 __attribute__((ext_vector_type(4)));
typedef unsigned short u16x8 __attribute__((ext_vector_type(8)));
typedef unsigned short u16x4 __attribute__((ext_vector_type(4)));

#define MFMA16(a, b, c) __builtin_amdgcn_mfma_f32_16x16x32_bf16(a, b, c, 0, 0, 0)

// native RNE f32->bf16
__device__ __forceinline__ unsigned short bfc(float x) {
    __bf16 b = (__bf16)x;
    return __builtin_bit_cast(unsigned short, b);
}

// async global->LDS, 16B per lane (HW: wave-uniform LDS base + lane*16)
__device__ __forceinline__ void gload16(const void* g, void* l) {
    __builtin_amdgcn_global_load_lds(
        (const __attribute__((address_space(1))) void*)g,
        (__attribute__((address_space(3))) void*)l, 16, 0, 0);
}

// log2(e) folding constants
#define QSCALE 0.18033688011112042f     // 0.125 * log2(e)
#define MASKVAL -28.853900817779268f    // -20 * log2(e)

// ------------------- prep: casts + weight transpose + mask pack -------------
__global__ __launch_bounds__(256) void prep_kern(
        const float* __restrict__ q, const float* __restrict__ k,
        const float* __restrict__ v, const int* __restrict__ mask,
        const float* __restrict__ Wq, const float* __restrict__ Wk,
        const float* __restrict__ Wv, const float* __restrict__ Wo,
        unsigned short* __restrict__ qb, unsigned short* __restrict__ kb,
        unsigned short* __restrict__ vb, unsigned short* __restrict__ wt,
        uint32_t* __restrict__ maskbits) {
    __shared__ float tile[32][33];
    const int x = blockIdx.x, t = threadIdx.x;
    if (x < 3072) {
        int which = x >> 10;
        const float* s = (which == 0) ? q : (which == 1) ? k : v;
        unsigned short* o = (which == 0) ? qb : (which == 1) ? kb : vb;
        int i = ((x & 1023) * 256 + t) * 4;
        float4 f = *(const float4*)&s[i];
        u16x4 r;
        r[0] = bfc(f.x); r[1] = bfc(f.y); r[2] = bfc(f.z); r[3] = bfc(f.w);
        *(u16x4*)&o[i] = r;
    } else if (x < 5120) {
        int y = x - 3072;
        int wsel = y >> 9;
        const float* W = (wsel == 0) ? Wq : (wsel == 1) ? Wk : (wsel == 2) ? Wv : Wo;
        unsigned short* T = wt + wsel * 2048 * 256;
        int rem = y & 511;
        int c0 = (rem & 63) * 32, r0 = (rem >> 6) * 32;
        int tr = t >> 3, tc = (t & 7) * 4;
        float4 f = *(const float4*)&W[(r0 + tr) * 2048 + c0 + tc];
        tile[tr][tc + 0] = f.x; tile[tr][tc + 1] = f.y;
        tile[tr][tc + 2] = f.z; tile[tr][tc + 3] = f.w;
        __syncthreads();
        u16x4 o;
        o[0] = bfc(tile[tc + 0][tr]); o[1] = bfc(tile[tc + 1][tr]);
        o[2] = bfc(tile[tc + 2][tr]); o[3] = bfc(tile[tc + 3][tr]);
        *(u16x4*)&T[(c0 + tr) * 256 + r0 + tc] = o;
    } else {
        // ballot mask-pack: wave reads 64 consecutive ints (256B coalesced),
        // ballot -> 2 bitwords. unit u = (b, row, ktpair); 32 units per wave.
        const int lane = t & 63;
        int wi = ((x - 5120) * 4 + (t >> 6)) * 32;
        for (int i = 0; i < 32; ++i) {
            int u = wi + i;
            int b = u >> 12, rem = u & 4095, row = rem >> 3, ktp = rem & 7;
            int mv = mask[((size_t)(b * 512 + row)) * 512 + ktp * 64 + lane];
            unsigned long long bal = __ballot(mv != 0);
            if (lane == 0) {
                maskbits[(size_t)(b * 16 + ktp * 2) * 512 + row] = (uint32_t)bal;
                maskbits[(size_t)(b * 16 + ktp * 2 + 1) * 512 + row] = (uint32_t)(bal >> 32);
            }
        }
    }
}

// --------------------- fused QKV projection + attention ---------------------
// Grid 256 (XCD-chunked: XCD x owns batch x), 1024 thr = 16 waves @ 4/SIMD.
__global__ __launch_bounds__(1024) void fused_kern(
        const unsigned short* __restrict__ actq,
        const unsigned short* __restrict__ actk,
        const unsigned short* __restrict__ actv,
        const unsigned short* __restrict__ Wt,      // [>=3][2048][256] bf16 (W^T)
        const uint32_t* __restrict__ maskbits,
        unsigned short* __restrict__ CTX) {
    __shared__ unsigned short Klds[512 * 64];   // 64 KB; Q-scratch before K-store
    __shared__ unsigned short Vt[64 * 512];     // 64 KB; V^T
    __shared__ unsigned short R3[64 * 128];     // 16 KB; W half-stage, then P
    const int bid = (int)blockIdx.x;
    const int flat = (bid & 7) * 32 + (bid >> 3);      // XCD-chunk: XCD = batch
    const int b = flat >> 5, eh = flat & 31;
    const int e = eh >> 2, h = eh & 3;
    const int t = threadIdx.x, w = t >> 6, l = t & 63, li = l & 15, g = l >> 4;
    const int tw0 = w * 32;                     // this wave's token/q-row base
    const size_t actoff = (size_t)b * 512 * 256;
    const size_t wso = ((size_t)(e * 256 + h * 64)) * 256;

    bf16x8 qf[2][2];

    // ---------------- projection phases (p = 0:Q, 1:K, 2:V) ----------------
    for (int p = 0; p < 3; ++p) {
        const unsigned short* A = ((p == 0) ? actq : (p == 1) ? actk : actv) + actoff;
        const unsigned short* W = Wt + (size_t)p * 2048 * 256 + wso;
        f32x4 acc[2][4];
#pragma unroll
        for (int m = 0; m < 2; ++m)
#pragma unroll
            for (int n = 0; n < 4; ++n) acc[m][n] = (f32x4){0.f, 0.f, 0.f, 0.f};
        for (int kh = 0; kh < 2; ++kh) {
            __syncthreads();   // prior R3 consumers done
            {   // stage 64x128 W half-panel: 1024 chunks of 16B, 16 per row
                int nr = t >> 4, k8 = (t & 15) * 8;
                *(u16x8*)&R3[nr * 128 + (k8 ^ ((nr & 7) << 3))] =
                    *(const u16x8*)&W[(size_t)nr * 256 + kh * 128 + k8];
            }
            __syncthreads();
#pragma unroll
            for (int kk = 0; kk < 4; ++kk) {
                const int k0 = kh * 128 + kk * 32;
                bf16x8 af[2], bfr[4];
#pragma unroll
                for (int m = 0; m < 2; ++m)
                    af[m] = *(const bf16x8*)&A[(size_t)(tw0 + m * 16 + li) * 256 + k0 + g * 8];
#pragma unroll
                for (int n = 0; n < 4; ++n) {
                    int nr = n * 16 + li;
                    bfr[n] = *(const bf16x8*)&R3[nr * 128 + ((kk * 32 + g * 8) ^ ((nr & 7) << 3))];
                }
                if (p == 2) {
#pragma unroll
                    for (int m = 0; m < 2; ++m)
#pragma unroll
                        for (int n = 0; n < 4; ++n)
                            acc[m][n] = MFMA16(af[m], bfr[n], acc[m][n]);   // C-layout
                } else {
#pragma unroll
                    for (int m = 0; m < 2; ++m)
#pragma unroll
                        for (int n = 0; n < 4; ++n)
                            acc[m][n] = MFMA16(bfr[n], af[m], acc[m][n]);   // C^T-layout
                }
            }
        }
        if (p == 0) {
            unsigned short* qs = Klds + w * 2048;   // 32 rows x 64, wave-private
#pragma unroll
            for (int m = 0; m < 2; ++m)
#pragma unroll
                for (int n = 0; n < 4; ++n) {
                    int row = m * 16 + li, dh = n * 16 + g * 4;
                    u16x4 o;
#pragma unroll
                    for (int i = 0; i < 4; ++i) o[i] = bfc(acc[m][n][i] * QSCALE);
                    *(u16x4*)&qs[row * 64 + (dh ^ ((row & 7) << 3))] = o;
                }
#pragma unroll
            for (int m = 0; m < 2; ++m) {
                int row = m * 16 + li;
                qf[m][0] = *(const bf16x8*)&qs[row * 64 + ((g * 8) ^ ((row & 7) << 3))];
                qf[m][1] = *(const bf16x8*)&qs[row * 64 + ((32 + g * 8) ^ ((row & 7) << 3))];
            }
        } else if (p == 1) {
#pragma unroll
            for (int m = 0; m < 2; ++m)
#pragma unroll
                for (int n = 0; n < 4; ++n) {
                    int tok = tw0 + m * 16 + li, dh = n * 16 + g * 4;
                    u16x4 o;
#pragma unroll
                    for (int i = 0; i < 4; ++i) o[i] = bfc(acc[m][n][i]);
                    *(u16x4*)&Klds[tok * 64 + (dh ^ (((tok >> 1) & 7) << 3))] = o;
                }
        } else {
#pragma unroll
            for (int m = 0; m < 2; ++m)
#pragma unroll
                for (int n = 0; n < 4; ++n) {
                    int tok = tw0 + m * 16 + g * 4, dh = n * 16 + li;
                    u16x4 o;
#pragma unroll
                    for (int i = 0; i < 4; ++i) o[i] = bfc(acc[m][n][i]);
                    *(u16x4*)&Vt[dh * 512 + (tok ^ ((dh & 7) << 3))] = o;
                }
        }
    }
    __syncthreads();   // K, V^T (and all R3 reads) complete

    // --------------------------- attention phase ---------------------------
    bf16x8 vaug;
#pragma unroll
    for (int j = 0; j < 8; ++j) vaug[j] = (li == 0) ? (__bf16)1.0f : (__bf16)0.0f;
    f32x4 atc[2][4], lacc[2];
#pragma unroll
    for (int m = 0; m < 2; ++m) {
#pragma unroll
        for (int c = 0; c < 4; ++c) atc[m][c] = (f32x4){0.f, 0.f, 0.f, 0.f};
        lacc[m] = (f32x4){0.f, 0.f, 0.f, 0.f};
    }
    unsigned short* Pw = R3 + w * 512;   // wave-private 16x32 P tile (1 KB)
    const uint32_t* mb = maskbits + (size_t)b * 16 * 512;

    for (int kt = 0; kt < 16; ++kt) {
        bf16x8 kf[2][2];
#pragma unroll
        for (int f = 0; f < 2; ++f) {
            int tok = kt * 32 + 2 * li + f;
            const unsigned short* kr = &Klds[tok * 64];
            int sw = ((tok >> 1) & 7) << 3;
            kf[f][0] = *(const bf16x8*)&kr[(g * 8) ^ sw];
            kf[f][1] = *(const bf16x8*)&kr[(32 + g * 8) ^ sw];
        }
        f32x4 s[2][2];
#pragma unroll
        for (int m = 0; m < 2; ++m)
#pragma unroll
            for (int f = 0; f < 2; ++f) {
                f32x4 zz = (f32x4){0.f, 0.f, 0.f, 0.f};
                zz = MFMA16(qf[m][0], kf[f][0], zz);
                zz = MFMA16(qf[m][1], kf[f][1], zz);
                s[m][f] = zz;
            }
#pragma unroll
        for (int m = 0; m < 2; ++m) {
            const uint4 mw = *(const uint4*)&mb[(size_t)kt * 512 +
                                                tw0 + m * 16 + g * 4];
#pragma unroll
            for (int i = 0; i < 4; ++i) {
                uint32_t word = (i == 0) ? mw.x : (i == 1) ? mw.y : (i == 2) ? mw.z : mw.w;
                uint32_t pair = (word >> (2 * li)) & 3u;
                if (pair & 1u) s[m][0][i] = MASKVAL;
                if (pair & 2u) s[m][1][i] = MASKVAL;
            }
        }
        bf16x8 bv[4];
#pragma unroll
        for (int c = 0; c < 4; ++c) {
            int dh = c * 16 + li;
            bv[c] = *(const bf16x8*)&Vt[dh * 512 + ((kt * 32 + g * 8) ^ ((dh & 7) << 3))];
        }
#pragma unroll
        for (int m = 0; m < 2; ++m) {
#pragma unroll
            for (int i = 0; i < 4; ++i) {
                int row = g * 4 + i;
                uint32_t pk = (uint32_t)bfc(__builtin_exp2f(s[m][0][i])) |
                              ((uint32_t)bfc(__builtin_exp2f(s[m][1][i])) << 16);
                *(uint32_t*)&Pw[row * 32 + ((2 * li) ^ ((row & 3) << 3))] = pk;
            }
            bf16x8 pa = *(const bf16x8*)&Pw[li * 32 + ((g * 8) ^ ((li & 3) << 3))];
#pragma unroll
            for (int c = 0; c < 4; ++c)
                atc[m][c] = MFMA16(bv[c], pa, atc[m][c]);
            lacc[m] = MFMA16(vaug, pa, lacc[m]);
        }
    }
#pragma unroll
    for (int m = 0; m < 2; ++m) {
        float l_i = __shfl(lacc[m][0], l & 15, 64);   // l_q at lane q, elem 0
        float inv = 1.0f / l_i;
        const int qrow = tw0 + m * 16 + li;
#pragma unroll
        for (int c = 0; c < 4; ++c) {
            u16x4 o;
#pragma unroll
            for (int i = 0; i < 4; ++i) o[i] = bfc(atc[m][c][i] * inv);
            *(u16x4*)&CTX[(size_t)((b * 512 + qrow) * 8 + e) * 256 +
                          h * 64 + c * 16 + g * 4] = o;
        }
    }
}

// ------------------------------- out GEMM ----------------------------------
// C[32768 x 2048] fp32 = CTX[32768 x 256](bf16) * Wo (as Wot[2048][256] bf16).
// global_load_lds staging + LDS-bounce epilogue (R11). Stores now go through
// L2 (plain stores) -- NT bypass removed.
__global__ __launch_bounds__(256) void gemm_kern(
        const unsigned short* __restrict__ A,
        const unsigned short* __restrict__ Bt,
        float* __restrict__ C, int cpx) {
    __shared__ __align__(16) unsigned char smem[32768];
    unsigned short* Asl = (unsigned short*)smem;            // 16 KB, linear
    unsigned short* Bsl = (unsigned short*)(smem + 16384);  // 16 KB, linear
    const int bid = (int)blockIdx.x;
    const int logical = (bid & 7) * cpx + (bid >> 3);
    const int bx = logical & 15;
    const int by = logical >> 4;
    const int t = threadIdx.x, l = t & 63, w = t >> 6;
    const int li = l & 15, g = l >> 4;
    const int wr = w >> 1, wc = w & 1;
    const int rowA = by * 128, colB = bx * 128;
    f32x4 acc[4][4];
#pragma unroll
    for (int m = 0; m < 4; ++m)
#pragma unroll
        for (int n = 0; n < 4; ++n) acc[m][n] = (f32x4){0.f, 0.f, 0.f, 0.f};

    for (int kk = 0; kk < 4; ++kk) {
        // stage A/B tiles: 1024 chunks each; inverse-swizzled global source
#pragma unroll
        for (int j = 0; j < 4; ++j) {
            const int seg = j * 4 + w;              // 0..15
            const int chunk = seg * 64 + l;         // 0..1023
            const int row = chunk >> 3, c8 = chunk & 7;
            const int src8 = (c8 ^ (row & 7)) * 8;  // inverse swizzle on source
            gload16(&A[(size_t)(rowA + row) * 256 + kk * 64 + src8],
                    &Asl[seg * 512]);
            gload16(&Bt[(size_t)(colB + row) * 256 + kk * 64 + src8],
                    &Bsl[seg * 512]);
        }
        __syncthreads();
#pragma unroll
        for (int hh = 0; hh < 2; ++hh) {
            bf16x8 af[4], bfr[4];
#pragma unroll
            for (int m = 0; m < 4; ++m) {
                int row = wr * 64 + m * 16 + li;
                af[m] = *(const bf16x8*)&Asl[row * 64 + (((hh * 4 + g) ^ (row & 7)) * 8)];
            }
#pragma unroll
            for (int n = 0; n < 4; ++n) {
                int row = wc * 64 + n * 16 + li;
                bfr[n] = *(const bf16x8*)&Bsl[row * 64 + (((hh * 4 + g) ^ (row & 7)) * 8)];
            }
#pragma unroll
            for (int m = 0; m < 4; ++m)
#pragma unroll
                for (int n = 0; n < 4; ++n)
                    acc[m][n] = MFMA16(bfr[n], af[m], acc[m][n]);   // C^T frag
        }
        __syncthreads();
    }
    // epilogue: wave-private LDS bounce -> 256B-contiguous row stores (via L2).
    float* osl = (float*)smem;
    const int wb = w * 1088;
#pragma unroll
    for (int m = 0; m < 4; ++m) {
#pragma unroll
        for (int n = 0; n < 4; ++n) {
            int c16 = (n * 4 + g) ^ (li & 3);
            *(f32x4*)&osl[wb + li * 68 + c16 * 4] = acc[m][n];
        }
#pragma unroll
        for (int r = 0; r < 4; ++r) {
            int chunk = r * 64 + l;
            int row = chunk >> 4, cic = chunk & 15;
            f32x4 v = *(const f32x4*)&osl[wb + row * 68 + (cic ^ (row & 3)) * 4];
            const int rr = rowA + wr * 64 + m * 16 + row;
            const int cc = colB + wc * 64 + cic * 4;
            *(f32x4*)&C[(size_t)rr * 2048 + cc] = v;
        }
    }
}

// ------------------------------- launch ------------------------------------
extern "C" void kernel_launch(void* const* d_in, const int* in_sizes, int n_in,
                              void* d_out, int out_size, void* d_ws, size_t ws_size,
                              hipStream_t stream) {
    (void)in_sizes; (void)n_in; (void)out_size; (void)ws_size;
    const float* queries = (const float*)d_in[0];
    const float* keys    = (const float*)d_in[1];
    const float* values  = (const float*)d_in[2];
    const int*   mask    = (const int*)d_in[3];
    const float* Wq = (const float*)d_in[4];
    const float* Wk = (const float*)d_in[5];
    const float* Wv = (const float*)d_in[6];
    const float* Wo = (const float*)d_in[7];

    unsigned short* CTX = (unsigned short*)d_ws;          // [32768][256] bf16
    unsigned short* Qbf = CTX + (size_t)32768 * 256;      // [3][4096][256] bf16
    unsigned short* Wt  = Qbf + (size_t)3 * 4096 * 256;   // [4][2048][256] bf16
    uint32_t* maskbits  = (uint32_t*)(Wt + (size_t)4 * 2048 * 256);  // [8][16][512]

    prep_kern<<<dim3(5376), 256, 0, stream>>>(queries, keys, values, mask,
                                              Wq, Wk, Wv, Wo,
                                              Qbf, Qbf + 4096 * 256, Qbf + 2 * 4096 * 256,
                                              Wt, maskbits);
    fused_kern<<<dim3(256), 1024, 0, stream>>>(Qbf, Qbf + 4096 * 256,
                                               Qbf + 2 * 4096 * 256,
                                               Wt, maskbits, CTX);
    gemm_kern<<<dim3(4096), 256, 0, stream>>>(CTX, Wt + (size_t)3 * 2048 * 256,
                                              (float*)d_out, 512);
}

// Round 13
// 143.589 us; speedup vs baseline: 1.0926x; 1.0926x over previous
//
#include <hip/hip_runtime.h>
#include <stdint.h>

// ---------------------------------------------------------------------------
// MultiExpertMultiHeadAttention  (B=8,S=512,D=256,E=8,H=4,DH=64)
// Round 13: revert to NT stores (R12 proved L2 write-allocate costs 17us);
// out-GEMM -> 256x256 tile, 8 waves, double-buffered global_load_lds
// prefetch (2-phase), LDS-bounce NT epilogue. prep+fused = R11 (verified).
// ---------------------------------------------------------------------------

typedef __bf16 bf16x8 __attribute__((ext_vector_type(8)));
typedef float f32x4 __attribute__((ext_vector_type(4)));
typedef unsigned short u16x8 __attribute__((ext_vector_type(8)));
typedef unsigned short u16x4 __attribute__((ext_vector_type(4)));

#define MFMA16(a, b, c) __builtin_amdgcn_mfma_f32_16x16x32_bf16(a, b, c, 0, 0, 0)

// native RNE f32->bf16
__device__ __forceinline__ unsigned short bfc(float x) {
    __bf16 b = (__bf16)x;
    return __builtin_bit_cast(unsigned short, b);
}

// async global->LDS, 16B per lane (HW: wave-uniform LDS base + lane*16)
__device__ __forceinline__ void gload16(const void* g, void* l) {
    __builtin_amdgcn_global_load_lds(
        (const __attribute__((address_space(1))) void*)g,
        (__attribute__((address_space(3))) void*)l, 16, 0, 0);
}

// log2(e) folding constants
#define QSCALE 0.18033688011112042f     // 0.125 * log2(e)
#define MASKVAL -28.853900817779268f    // -20 * log2(e)

// ------------------- prep: casts + weight transpose + mask pack -------------
__global__ __launch_bounds__(256) void prep_kern(
        const float* __restrict__ q, const float* __restrict__ k,
        const float* __restrict__ v, const int* __restrict__ mask,
        const float* __restrict__ Wq, const float* __restrict__ Wk,
        const float* __restrict__ Wv, const float* __restrict__ Wo,
        unsigned short* __restrict__ qb, unsigned short* __restrict__ kb,
        unsigned short* __restrict__ vb, unsigned short* __restrict__ wt,
        uint32_t* __restrict__ maskbits) {
    __shared__ float tile[32][33];
    const int x = blockIdx.x, t = threadIdx.x;
    if (x < 3072) {
        int which = x >> 10;
        const float* s = (which == 0) ? q : (which == 1) ? k : v;
        unsigned short* o = (which == 0) ? qb : (which == 1) ? kb : vb;
        int i = ((x & 1023) * 256 + t) * 4;
        float4 f = *(const float4*)&s[i];
        u16x4 r;
        r[0] = bfc(f.x); r[1] = bfc(f.y); r[2] = bfc(f.z); r[3] = bfc(f.w);
        *(u16x4*)&o[i] = r;
    } else if (x < 5120) {
        int y = x - 3072;
        int wsel = y >> 9;
        const float* W = (wsel == 0) ? Wq : (wsel == 1) ? Wk : (wsel == 2) ? Wv : Wo;
        unsigned short* T = wt + wsel * 2048 * 256;
        int rem = y & 511;
        int c0 = (rem & 63) * 32, r0 = (rem >> 6) * 32;
        int tr = t >> 3, tc = (t & 7) * 4;
        float4 f = *(const float4*)&W[(r0 + tr) * 2048 + c0 + tc];
        tile[tr][tc + 0] = f.x; tile[tr][tc + 1] = f.y;
        tile[tr][tc + 2] = f.z; tile[tr][tc + 3] = f.w;
        __syncthreads();
        u16x4 o;
        o[0] = bfc(tile[tc + 0][tr]); o[1] = bfc(tile[tc + 1][tr]);
        o[2] = bfc(tile[tc + 2][tr]); o[3] = bfc(tile[tc + 3][tr]);
        *(u16x4*)&T[(c0 + tr) * 256 + r0 + tc] = o;
    } else {
        // ballot mask-pack: wave reads 64 consecutive ints (256B coalesced),
        // ballot -> 2 bitwords. unit u = (b, row, ktpair); 32 units per wave.
        const int lane = t & 63;
        int wi = ((x - 5120) * 4 + (t >> 6)) * 32;
        for (int i = 0; i < 32; ++i) {
            int u = wi + i;
            int b = u >> 12, rem = u & 4095, row = rem >> 3, ktp = rem & 7;
            int mv = mask[((size_t)(b * 512 + row)) * 512 + ktp * 64 + lane];
            unsigned long long bal = __ballot(mv != 0);
            if (lane == 0) {
                maskbits[(size_t)(b * 16 + ktp * 2) * 512 + row] = (uint32_t)bal;
                maskbits[(size_t)(b * 16 + ktp * 2 + 1) * 512 + row] = (uint32_t)(bal >> 32);
            }
        }
    }
}

// --------------------- fused QKV projection + attention ---------------------
// Grid 256 (XCD-chunked: XCD x owns batch x), 1024 thr = 16 waves @ 4/SIMD.
__global__ __launch_bounds__(1024) void fused_kern(
        const unsigned short* __restrict__ actq,
        const unsigned short* __restrict__ actk,
        const unsigned short* __restrict__ actv,
        const unsigned short* __restrict__ Wt,      // [>=3][2048][256] bf16 (W^T)
        const uint32_t* __restrict__ maskbits,
        unsigned short* __restrict__ CTX) {
    __shared__ unsigned short Klds[512 * 64];   // 64 KB; Q-scratch before K-store
    __shared__ unsigned short Vt[64 * 512];     // 64 KB; V^T
    __shared__ unsigned short R3[64 * 128];     // 16 KB; W half-stage, then P
    const int bid = (int)blockIdx.x;
    const int flat = (bid & 7) * 32 + (bid >> 3);      // XCD-chunk: XCD = batch
    const int b = flat >> 5, eh = flat & 31;
    const int e = eh >> 2, h = eh & 3;
    const int t = threadIdx.x, w = t >> 6, l = t & 63, li = l & 15, g = l >> 4;
    const int tw0 = w * 32;                     // this wave's token/q-row base
    const size_t actoff = (size_t)b * 512 * 256;
    const size_t wso = ((size_t)(e * 256 + h * 64)) * 256;

    bf16x8 qf[2][2];

    // ---------------- projection phases (p = 0:Q, 1:K, 2:V) ----------------
    for (int p = 0; p < 3; ++p) {
        const unsigned short* A = ((p == 0) ? actq : (p == 1) ? actk : actv) + actoff;
        const unsigned short* W = Wt + (size_t)p * 2048 * 256 + wso;
        f32x4 acc[2][4];
#pragma unroll
        for (int m = 0; m < 2; ++m)
#pragma unroll
            for (int n = 0; n < 4; ++n) acc[m][n] = (f32x4){0.f, 0.f, 0.f, 0.f};
        for (int kh = 0; kh < 2; ++kh) {
            __syncthreads();   // prior R3 consumers done
            {   // stage 64x128 W half-panel: 1024 chunks of 16B, 16 per row
                int nr = t >> 4, k8 = (t & 15) * 8;
                *(u16x8*)&R3[nr * 128 + (k8 ^ ((nr & 7) << 3))] =
                    *(const u16x8*)&W[(size_t)nr * 256 + kh * 128 + k8];
            }
            __syncthreads();
#pragma unroll
            for (int kk = 0; kk < 4; ++kk) {
                const int k0 = kh * 128 + kk * 32;
                bf16x8 af[2], bfr[4];
#pragma unroll
                for (int m = 0; m < 2; ++m)
                    af[m] = *(const bf16x8*)&A[(size_t)(tw0 + m * 16 + li) * 256 + k0 + g * 8];
#pragma unroll
                for (int n = 0; n < 4; ++n) {
                    int nr = n * 16 + li;
                    bfr[n] = *(const bf16x8*)&R3[nr * 128 + ((kk * 32 + g * 8) ^ ((nr & 7) << 3))];
                }
                if (p == 2) {
#pragma unroll
                    for (int m = 0; m < 2; ++m)
#pragma unroll
                        for (int n = 0; n < 4; ++n)
                            acc[m][n] = MFMA16(af[m], bfr[n], acc[m][n]);   // C-layout
                } else {
#pragma unroll
                    for (int m = 0; m < 2; ++m)
#pragma unroll
                        for (int n = 0; n < 4; ++n)
                            acc[m][n] = MFMA16(bfr[n], af[m], acc[m][n]);   // C^T-layout
                }
            }
        }
        if (p == 0) {
            unsigned short* qs = Klds + w * 2048;   // 32 rows x 64, wave-private
#pragma unroll
            for (int m = 0; m < 2; ++m)
#pragma unroll
                for (int n = 0; n < 4; ++n) {
                    int row = m * 16 + li, dh = n * 16 + g * 4;
                    u16x4 o;
#pragma unroll
                    for (int i = 0; i < 4; ++i) o[i] = bfc(acc[m][n][i] * QSCALE);
                    *(u16x4*)&qs[row * 64 + (dh ^ ((row & 7) << 3))] = o;
                }
#pragma unroll
            for (int m = 0; m < 2; ++m) {
                int row = m * 16 + li;
                qf[m][0] = *(const bf16x8*)&qs[row * 64 + ((g * 8) ^ ((row & 7) << 3))];
                qf[m][1] = *(const bf16x8*)&qs[row * 64 + ((32 + g * 8) ^ ((row & 7) << 3))];
            }
        } else if (p == 1) {
#pragma unroll
            for (int m = 0; m < 2; ++m)
#pragma unroll
                for (int n = 0; n < 4; ++n) {
                    int tok = tw0 + m * 16 + li, dh = n * 16 + g * 4;
                    u16x4 o;
#pragma unroll
                    for (int i = 0; i < 4; ++i) o[i] = bfc(acc[m][n][i]);
                    *(u16x4*)&Klds[tok * 64 + (dh ^ (((tok >> 1) & 7) << 3))] = o;
                }
        } else {
#pragma unroll
            for (int m = 0; m < 2; ++m)
#pragma unroll
                for (int n = 0; n < 4; ++n) {
                    int tok = tw0 + m * 16 + g * 4, dh = n * 16 + li;
                    u16x4 o;
#pragma unroll
                    for (int i = 0; i < 4; ++i) o[i] = bfc(acc[m][n][i]);
                    *(u16x4*)&Vt[dh * 512 + (tok ^ ((dh & 7) << 3))] = o;
                }
        }
    }
    __syncthreads();   // K, V^T (and all R3 reads) complete

    // --------------------------- attention phase ---------------------------
    bf16x8 vaug;
#pragma unroll
    for (int j = 0; j < 8; ++j) vaug[j] = (li == 0) ? (__bf16)1.0f : (__bf16)0.0f;
    f32x4 atc[2][4], lacc[2];
#pragma unroll
    for (int m = 0; m < 2; ++m) {
#pragma unroll
        for (int c = 0; c < 4; ++c) atc[m][c] = (f32x4){0.f, 0.f, 0.f, 0.f};
        lacc[m] = (f32x4){0.f, 0.f, 0.f, 0.f};
    }
    unsigned short* Pw = R3 + w * 512;   // wave-private 16x32 P tile (1 KB)
    const uint32_t* mb = maskbits + (size_t)b * 16 * 512;

    for (int kt = 0; kt < 16; ++kt) {
        bf16x8 kf[2][2];
#pragma unroll
        for (int f = 0; f < 2; ++f) {
            int tok = kt * 32 + 2 * li + f;
            const unsigned short* kr = &Klds[tok * 64];
            int sw = ((tok >> 1) & 7) << 3;
            kf[f][0] = *(const bf16x8*)&kr[(g * 8) ^ sw];
            kf[f][1] = *(const bf16x8*)&kr[(32 + g * 8) ^ sw];
        }
        f32x4 s[2][2];
#pragma unroll
        for (int m = 0; m < 2; ++m)
#pragma unroll
            for (int f = 0; f < 2; ++f) {
                f32x4 zz = (f32x4){0.f, 0.f, 0.f, 0.f};
                zz = MFMA16(qf[m][0], kf[f][0], zz);
                zz = MFMA16(qf[m][1], kf[f][1], zz);
                s[m][f] = zz;
            }
#pragma unroll
        for (int m = 0; m < 2; ++m) {
            const uint4 mw = *(const uint4*)&mb[(size_t)kt * 512 +
                                                tw0 + m * 16 + g * 4];
#pragma unroll
            for (int i = 0; i < 4; ++i) {
                uint32_t word = (i == 0) ? mw.x : (i == 1) ? mw.y : (i == 2) ? mw.z : mw.w;
                uint32_t pair = (word >> (2 * li)) & 3u;
                if (pair & 1u) s[m][0][i] = MASKVAL;
                if (pair & 2u) s[m][1][i] = MASKVAL;
            }
        }
        bf16x8 bv[4];
#pragma unroll
        for (int c = 0; c < 4; ++c) {
            int dh = c * 16 + li;
            bv[c] = *(const bf16x8*)&Vt[dh * 512 + ((kt * 32 + g * 8) ^ ((dh & 7) << 3))];
        }
#pragma unroll
        for (int m = 0; m < 2; ++m) {
#pragma unroll
            for (int i = 0; i < 4; ++i) {
                int row = g * 4 + i;
                uint32_t pk = (uint32_t)bfc(__builtin_exp2f(s[m][0][i])) |
                              ((uint32_t)bfc(__builtin_exp2f(s[m][1][i])) << 16);
                *(uint32_t*)&Pw[row * 32 + ((2 * li) ^ ((row & 3) << 3))] = pk;
            }
            bf16x8 pa = *(const bf16x8*)&Pw[li * 32 + ((g * 8) ^ ((li & 3) << 3))];
#pragma unroll
            for (int c = 0; c < 4; ++c)
                atc[m][c] = MFMA16(bv[c], pa, atc[m][c]);
            lacc[m] = MFMA16(vaug, pa, lacc[m]);
        }
    }
#pragma unroll
    for (int m = 0; m < 2; ++m) {
        float l_i = __shfl(lacc[m][0], l & 15, 64);   // l_q at lane q, elem 0
        float inv = 1.0f / l_i;
        const int qrow = tw0 + m * 16 + li;
#pragma unroll
        for (int c = 0; c < 4; ++c) {
            u16x4 o;
#pragma unroll
            for (int i = 0; i < 4; ++i) o[i] = bfc(atc[m][c][i] * inv);
            *(u16x4*)&CTX[(size_t)((b * 512 + qrow) * 8 + e) * 256 +
                          h * 64 + c * 16 + g * 4] = o;
        }
    }
}

// ------------------------------- out GEMM ----------------------------------
// C[32768 x 2048] fp32 = CTX[32768 x 256](bf16) * Wo (as Wot[2048][256]).
// 256x256 tile, 512 thr (8 waves, 2Mx4N; per-wave 128x64), double-buffered
// global_load_lds prefetch (STAGE(t+1) before compute(t), 1 barrier/iter),
// LDS-bounce epilogue with NT stores.
__global__ __launch_bounds__(512, 2) void gemm_kern(
        const unsigned short* __restrict__ A,
        const unsigned short* __restrict__ Bt,
        float* __restrict__ C) {
    __shared__ __align__(16) unsigned char smem[131072];   // 2 x (32KB A + 32KB B)
    const int bid = (int)blockIdx.x;
    const int logical = (bid & 7) * 128 + (bid >> 3);
    const int bx = logical & 7;
    const int by = logical >> 3;
    const int t = threadIdx.x, l = t & 63, w = t >> 6;
    const int li = l & 15, g = l >> 4;
    const int wr = w >> 2, wcn = w & 3;
    const int rowA = by * 256, colB = bx * 256;

    f32x4 acc[8][4];
#pragma unroll
    for (int m = 0; m < 8; ++m)
#pragma unroll
        for (int n = 0; n < 4; ++n) acc[m][n] = (f32x4){0.f, 0.f, 0.f, 0.f};

    // stage K-tile kk into buffer bsel: 2048 chunks per matrix, 4 calls/wave
    auto STAGE = [&](int kk, int bsel) {
        unsigned short* Ad = (unsigned short*)smem + bsel * 32768;
        unsigned short* Bd = Ad + 16384;
#pragma unroll
        for (int j = 0; j < 4; ++j) {
            const int seg = j * 8 + w;              // 0..31
            const int chunk = seg * 64 + l;         // 0..2047
            const int row = chunk >> 3, c8 = chunk & 7;
            const int src8 = (c8 ^ (row & 7)) * 8;  // inverse swizzle on source
            gload16(&A[(size_t)(rowA + row) * 256 + kk * 64 + src8], &Ad[seg * 512]);
            gload16(&Bt[(size_t)(colB + row) * 256 + kk * 64 + src8], &Bd[seg * 512]);
        }
    };

    STAGE(0, 0);
    __syncthreads();        // buf0 ready (barrier drains vmcnt)
    for (int kk = 0; kk < 4; ++kk) {
        if (kk < 3) STAGE(kk + 1, (kk + 1) & 1);   // prefetch flies under MFMA
        const unsigned short* Ad = (const unsigned short*)smem + (kk & 1) * 32768;
        const unsigned short* Bd = Ad + 16384;
#pragma unroll
        for (int hh = 0; hh < 2; ++hh) {
            bf16x8 bfr[4];
#pragma unroll
            for (int n = 0; n < 4; ++n) {
                int c = wcn * 64 + n * 16 + li;
                bfr[n] = *(const bf16x8*)&Bd[c * 64 + (((hh * 4 + g) ^ (c & 7)) * 8)];
            }
#pragma unroll
            for (int m = 0; m < 8; ++m) {
                int r = wr * 128 + m * 16 + li;
                bf16x8 af = *(const bf16x8*)&Ad[r * 64 + (((hh * 4 + g) ^ (r & 7)) * 8)];
#pragma unroll
                for (int n = 0; n < 4; ++n)
                    acc[m][n] = MFMA16(bfr[n], af, acc[m][n]);   // C^T frag
            }
        }
        __syncthreads();    // all reads of buf[kk&1] done; prefetch landed
    }
    // epilogue: wave-private LDS bounce -> 256B-contiguous NT row stores
    float* osl = (float*)smem;
    const int wb = w * 1088;       // 16 rows x 68 floats per wave
#pragma unroll
    for (int m = 0; m < 8; ++m) {
#pragma unroll
        for (int n = 0; n < 4; ++n) {
            int c16 = (n * 4 + g) ^ (li & 3);
            *(f32x4*)&osl[wb + li * 68 + c16 * 4] = acc[m][n];
        }
#pragma unroll
        for (int r = 0; r < 4; ++r) {
            int chunk = r * 64 + l;
            int row = chunk >> 4, cic = chunk & 15;
            f32x4 v = *(const f32x4*)&osl[wb + row * 68 + (cic ^ (row & 3)) * 4];
            const int rr = rowA + wr * 128 + m * 16 + row;
            const int cc = colB + wcn * 64 + cic * 4;
            __builtin_nontemporal_store(v, (f32x4*)&C[(size_t)rr * 2048 + cc]);
        }
    }
}

// ------------------------------- launch ------------------------------------
extern "C" void kernel_launch(void* const* d_in, const int* in_sizes, int n_in,
                              void* d_out, int out_size, void* d_ws, size_t ws_size,
                              hipStream_t stream) {
    (void)in_sizes; (void)n_in; (void)out_size; (void)ws_size;
    const float* queries = (const float*)d_in[0];
    const float* keys    = (const float*)d_in[1];
    const float* values  = (const float*)d_in[2];
    const int*   mask    = (const int*)d_in[3];
    const float* Wq = (const float*)d_in[4];
    const float* Wk = (const float*)d_in[5];
    const float* Wv = (const float*)d_in[6];
    const float* Wo = (const float*)d_in[7];

    unsigned short* CTX = (unsigned short*)d_ws;          // [32768][256] bf16
    unsigned short* Qbf = CTX + (size_t)32768 * 256;      // [3][4096][256] bf16
    unsigned short* Wt  = Qbf + (size_t)3 * 4096 * 256;   // [4][2048][256] bf16
    uint32_t* maskbits  = (uint32_t*)(Wt + (size_t)4 * 2048 * 256);  // [8][16][512]

    prep_kern<<<dim3(5376), 256, 0, stream>>>(queries, keys, values, mask,
                                              Wq, Wk, Wv, Wo,
                                              Qbf, Qbf + 4096 * 256, Qbf + 2 * 4096 * 256,
                                              Wt, maskbits);
    fused_kern<<<dim3(256), 1024, 0, stream>>>(Qbf, Qbf + 4096 * 256,
                                               Qbf + 2 * 4096 * 256,
                                               Wt, maskbits, CTX);
    gemm_kern<<<dim3(1024), 512, 0, stream>>>(CTX, Wt + (size_t)3 * 2048 * 256,
                                              (float*)d_out);
}

// Round 14
// 139.361 us; speedup vs baseline: 1.1258x; 1.0303x over previous
//
#include <hip/hip_runtime.h>
#include <stdint.h>

// ---------------------------------------------------------------------------
// MultiExpertMultiHeadAttention  (B=8,S=512,D=256,E=8,H=4,DH=64)
// Round 14: out-GEMM reverted to R11 (128^2, NT stores, 4 blocks/CU — R13's
// 256^2 regressed). Fused kernel: W-staging via async global_load_lds into
// double-buffered R3 (one barrier per phase, 13 -> 7 barriers), LDS = 160 KiB.
// ---------------------------------------------------------------------------

typedef __bf16 bf16x8 __attribute__((ext_vector_type(8)));
typedef float f32x4 __attribute__((ext_vector_type(4)));
typedef unsigned short u16x8 __attribute__((ext_vector_type(8)));
typedef unsigned short u16x4 __attribute__((ext_vector_type(4)));

#define MFMA16(a, b, c) __builtin_amdgcn_mfma_f32_16x16x32_bf16(a, b, c, 0, 0, 0)

// native RNE f32->bf16
__device__ __forceinline__ unsigned short bfc(float x) {
    __bf16 b = (__bf16)x;
    return __builtin_bit_cast(unsigned short, b);
}

// async global->LDS, 16B per lane (HW: wave-uniform LDS base + lane*16)
__device__ __forceinline__ void gload16(const void* g, void* l) {
    __builtin_amdgcn_global_load_lds(
        (const __attribute__((address_space(1))) void*)g,
        (__attribute__((address_space(3))) void*)l, 16, 0, 0);
}

// log2(e) folding constants
#define QSCALE 0.18033688011112042f     // 0.125 * log2(e)
#define MASKVAL -28.853900817779268f    // -20 * log2(e)

// ------------------- prep: casts + weight transpose + mask pack -------------
__global__ __launch_bounds__(256) void prep_kern(
        const float* __restrict__ q, const float* __restrict__ k,
        const float* __restrict__ v, const int* __restrict__ mask,
        const float* __restrict__ Wq, const float* __restrict__ Wk,
        const float* __restrict__ Wv, const float* __restrict__ Wo,
        unsigned short* __restrict__ qb, unsigned short* __restrict__ kb,
        unsigned short* __restrict__ vb, unsigned short* __restrict__ wt,
        uint32_t* __restrict__ maskbits) {
    __shared__ float tile[32][33];
    const int x = blockIdx.x, t = threadIdx.x;
    if (x < 3072) {
        int which = x >> 10;
        const float* s = (which == 0) ? q : (which == 1) ? k : v;
        unsigned short* o = (which == 0) ? qb : (which == 1) ? kb : vb;
        int i = ((x & 1023) * 256 + t) * 4;
        float4 f = *(const float4*)&s[i];
        u16x4 r;
        r[0] = bfc(f.x); r[1] = bfc(f.y); r[2] = bfc(f.z); r[3] = bfc(f.w);
        *(u16x4*)&o[i] = r;
    } else if (x < 5120) {
        int y = x - 3072;
        int wsel = y >> 9;
        const float* W = (wsel == 0) ? Wq : (wsel == 1) ? Wk : (wsel == 2) ? Wv : Wo;
        unsigned short* T = wt + wsel * 2048 * 256;
        int rem = y & 511;
        int c0 = (rem & 63) * 32, r0 = (rem >> 6) * 32;
        int tr = t >> 3, tc = (t & 7) * 4;
        float4 f = *(const float4*)&W[(r0 + tr) * 2048 + c0 + tc];
        tile[tr][tc + 0] = f.x; tile[tr][tc + 1] = f.y;
        tile[tr][tc + 2] = f.z; tile[tr][tc + 3] = f.w;
        __syncthreads();
        u16x4 o;
        o[0] = bfc(tile[tc + 0][tr]); o[1] = bfc(tile[tc + 1][tr]);
        o[2] = bfc(tile[tc + 2][tr]); o[3] = bfc(tile[tc + 3][tr]);
        *(u16x4*)&T[(c0 + tr) * 256 + r0 + tc] = o;
    } else {
        // ballot mask-pack: wave reads 64 consecutive ints (256B coalesced),
        // ballot -> 2 bitwords. unit u = (b, row, ktpair); 32 units per wave.
        const int lane = t & 63;
        int wi = ((x - 5120) * 4 + (t >> 6)) * 32;
        for (int i = 0; i < 32; ++i) {
            int u = wi + i;
            int b = u >> 12, rem = u & 4095, row = rem >> 3, ktp = rem & 7;
            int mv = mask[((size_t)(b * 512 + row)) * 512 + ktp * 64 + lane];
            unsigned long long bal = __ballot(mv != 0);
            if (lane == 0) {
                maskbits[(size_t)(b * 16 + ktp * 2) * 512 + row] = (uint32_t)bal;
                maskbits[(size_t)(b * 16 + ktp * 2 + 1) * 512 + row] = (uint32_t)(bal >> 32);
            }
        }
    }
}

// --------------------- fused QKV projection + attention ---------------------
// Grid 256 (XCD-chunked: XCD x owns batch x), 1024 thr = 16 waves @ 4/SIMD.
// W staged via async global_load_lds into double-buffered R3 (1 barrier/phase).
__global__ __launch_bounds__(1024) void fused_kern(
        const unsigned short* __restrict__ actq,
        const unsigned short* __restrict__ actk,
        const unsigned short* __restrict__ actv,
        const unsigned short* __restrict__ Wt,      // [>=3][2048][256] bf16 (W^T)
        const uint32_t* __restrict__ maskbits,
        unsigned short* __restrict__ CTX) {
    __shared__ unsigned short Klds[512 * 64];   // 64 KB; Q-scratch before K-store
    __shared__ unsigned short Vt[64 * 512];     // 64 KB; V^T
    __shared__ unsigned short R3[2][64 * 128];  // 32 KB dbuf; P tiles in attn
    const int bid = (int)blockIdx.x;
    const int flat = (bid & 7) * 32 + (bid >> 3);      // XCD-chunk: XCD = batch
    const int b = flat >> 5, eh = flat & 31;
    const int e = eh >> 2, h = eh & 3;
    const int t = threadIdx.x, w = t >> 6, l = t & 63, li = l & 15, g = l >> 4;
    const int tw0 = w * 32;                     // this wave's token/q-row base
    const size_t actoff = (size_t)b * 512 * 256;
    const size_t wso = ((size_t)(e * 256 + h * 64)) * 256;

    bf16x8 qf[2][2];

    // async stage of W half-panel `unit` (p=unit>>1, kh=unit&1) into R3[unit&1]
    // linear LDS dest + inverse-swizzled per-lane global src (content identical
    // to swizzled-store layout, so reads use the same XOR).
    auto STAGEW = [&](int unit) {
        const unsigned short* W = Wt + (size_t)(unit >> 1) * 2048 * 256 + wso +
                                  (unit & 1) * 128;
        const int nr = (w << 2) + (l >> 4), cic = l & 15;
        gload16(&W[(size_t)nr * 256 + ((cic ^ (nr & 7)) << 3)],
                &R3[unit & 1][w * 512]);
    };

    STAGEW(0);
    __syncthreads();   // initial W half staged (barrier drains vmcnt)

    // ---------------- projection phases (p = 0:Q, 1:K, 2:V) ----------------
    for (int p = 0; p < 3; ++p) {
        const unsigned short* A = ((p == 0) ? actq : (p == 1) ? actk : actv) + actoff;
        f32x4 acc[2][4];
#pragma unroll
        for (int m = 0; m < 2; ++m)
#pragma unroll
            for (int n = 0; n < 4; ++n) acc[m][n] = (f32x4){0.f, 0.f, 0.f, 0.f};
#pragma unroll
        for (int kh = 0; kh < 2; ++kh) {
            const int unit = p * 2 + kh;
            if (unit < 5) STAGEW(unit + 1);          // async prefetch next panel
            const unsigned short* cur = R3[unit & 1];
#pragma unroll
            for (int kk = 0; kk < 4; ++kk) {
                const int k0 = kh * 128 + kk * 32;
                bf16x8 af[2], bfr[4];
#pragma unroll
                for (int m = 0; m < 2; ++m)
                    af[m] = *(const bf16x8*)&A[(size_t)(tw0 + m * 16 + li) * 256 + k0 + g * 8];
#pragma unroll
                for (int n = 0; n < 4; ++n) {
                    int nr = n * 16 + li;
                    bfr[n] = *(const bf16x8*)&cur[nr * 128 + ((kk * 32 + g * 8) ^ ((nr & 7) << 3))];
                }
                if (p == 2) {
#pragma unroll
                    for (int m = 0; m < 2; ++m)
#pragma unroll
                        for (int n = 0; n < 4; ++n)
                            acc[m][n] = MFMA16(af[m], bfr[n], acc[m][n]);   // C-layout
                } else {
#pragma unroll
                    for (int m = 0; m < 2; ++m)
#pragma unroll
                        for (int n = 0; n < 4; ++n)
                            acc[m][n] = MFMA16(bfr[n], af[m], acc[m][n]);   // C^T-layout
                }
            }
            __syncthreads();   // readers of cur done; next panel's loads drained
        }
        if (p == 0) {
            unsigned short* qs = Klds + w * 2048;   // 32 rows x 64, wave-private
#pragma unroll
            for (int m = 0; m < 2; ++m)
#pragma unroll
                for (int n = 0; n < 4; ++n) {
                    int row = m * 16 + li, dh = n * 16 + g * 4;
                    u16x4 o;
#pragma unroll
                    for (int i = 0; i < 4; ++i) o[i] = bfc(acc[m][n][i] * QSCALE);
                    *(u16x4*)&qs[row * 64 + (dh ^ ((row & 7) << 3))] = o;
                }
#pragma unroll
            for (int m = 0; m < 2; ++m) {
                int row = m * 16 + li;
                qf[m][0] = *(const bf16x8*)&qs[row * 64 + ((g * 8) ^ ((row & 7) << 3))];
                qf[m][1] = *(const bf16x8*)&qs[row * 64 + ((32 + g * 8) ^ ((row & 7) << 3))];
            }
        } else if (p == 1) {
            // wave's K token range == its own Q-scratch region: wave-private
#pragma unroll
            for (int m = 0; m < 2; ++m)
#pragma unroll
                for (int n = 0; n < 4; ++n) {
                    int tok = tw0 + m * 16 + li, dh = n * 16 + g * 4;
                    u16x4 o;
#pragma unroll
                    for (int i = 0; i < 4; ++i) o[i] = bfc(acc[m][n][i]);
                    *(u16x4*)&Klds[tok * 64 + (dh ^ (((tok >> 1) & 7) << 3))] = o;
                }
        } else {
#pragma unroll
            for (int m = 0; m < 2; ++m)
#pragma unroll
                for (int n = 0; n < 4; ++n) {
                    int tok = tw0 + m * 16 + g * 4, dh = n * 16 + li;
                    u16x4 o;
#pragma unroll
                    for (int i = 0; i < 4; ++i) o[i] = bfc(acc[m][n][i]);
                    *(u16x4*)&Vt[dh * 512 + (tok ^ ((dh & 7) << 3))] = o;
                }
        }
    }
    __syncthreads();   // K, V^T (and all R3 reads) complete

    // --------------------------- attention phase ---------------------------
    bf16x8 vaug;
#pragma unroll
    for (int j = 0; j < 8; ++j) vaug[j] = (li == 0) ? (__bf16)1.0f : (__bf16)0.0f;
    f32x4 atc[2][4], lacc[2];
#pragma unroll
    for (int m = 0; m < 2; ++m) {
#pragma unroll
        for (int c = 0; c < 4; ++c) atc[m][c] = (f32x4){0.f, 0.f, 0.f, 0.f};
        lacc[m] = (f32x4){0.f, 0.f, 0.f, 0.f};
    }
    unsigned short* Pw = &R3[0][0] + w * 512;   // wave-private 16x32 P tile
    const uint32_t* mb = maskbits + (size_t)b * 16 * 512;

    for (int kt = 0; kt < 16; ++kt) {
        bf16x8 kf[2][2];
#pragma unroll
        for (int f = 0; f < 2; ++f) {
            int tok = kt * 32 + 2 * li + f;
            const unsigned short* kr = &Klds[tok * 64];
            int sw = ((tok >> 1) & 7) << 3;
            kf[f][0] = *(const bf16x8*)&kr[(g * 8) ^ sw];
            kf[f][1] = *(const bf16x8*)&kr[(32 + g * 8) ^ sw];
        }
        f32x4 s[2][2];
#pragma unroll
        for (int m = 0; m < 2; ++m)
#pragma unroll
            for (int f = 0; f < 2; ++f) {
                f32x4 zz = (f32x4){0.f, 0.f, 0.f, 0.f};
                zz = MFMA16(qf[m][0], kf[f][0], zz);
                zz = MFMA16(qf[m][1], kf[f][1], zz);
                s[m][f] = zz;
            }
#pragma unroll
        for (int m = 0; m < 2; ++m) {
            const uint4 mw = *(const uint4*)&mb[(size_t)kt * 512 +
                                                tw0 + m * 16 + g * 4];
#pragma unroll
            for (int i = 0; i < 4; ++i) {
                uint32_t word = (i == 0) ? mw.x : (i == 1) ? mw.y : (i == 2) ? mw.z : mw.w;
                uint32_t pair = (word >> (2 * li)) & 3u;
                if (pair & 1u) s[m][0][i] = MASKVAL;
                if (pair & 2u) s[m][1][i] = MASKVAL;
            }
        }
        bf16x8 bv[4];
#pragma unroll
        for (int c = 0; c < 4; ++c) {
            int dh = c * 16 + li;
            bv[c] = *(const bf16x8*)&Vt[dh * 512 + ((kt * 32 + g * 8) ^ ((dh & 7) << 3))];
        }
#pragma unroll
        for (int m = 0; m < 2; ++m) {
#pragma unroll
            for (int i = 0; i < 4; ++i) {
                int row = g * 4 + i;
                uint32_t pk = (uint32_t)bfc(__builtin_exp2f(s[m][0][i])) |
                              ((uint32_t)bfc(__builtin_exp2f(s[m][1][i])) << 16);
                *(uint32_t*)&Pw[row * 32 + ((2 * li) ^ ((row & 3) << 3))] = pk;
            }
            bf16x8 pa = *(const bf16x8*)&Pw[li * 32 + ((g * 8) ^ ((li & 3) << 3))];
#pragma unroll
            for (int c = 0; c < 4; ++c)
                atc[m][c] = MFMA16(bv[c], pa, atc[m][c]);
            lacc[m] = MFMA16(vaug, pa, lacc[m]);
        }
    }
#pragma unroll
    for (int m = 0; m < 2; ++m) {
        float l_i = __shfl(lacc[m][0], l & 15, 64);   // l_q at lane q, elem 0
        float inv = 1.0f / l_i;
        const int qrow = tw0 + m * 16 + li;
#pragma unroll
        for (int c = 0; c < 4; ++c) {
            u16x4 o;
#pragma unroll
            for (int i = 0; i < 4; ++i) o[i] = bfc(atc[m][c][i] * inv);
            *(u16x4*)&CTX[(size_t)((b * 512 + qrow) * 8 + e) * 256 +
                          h * 64 + c * 16 + g * 4] = o;
        }
    }
}

// ------------------------------- out GEMM ----------------------------------
// C[32768 x 2048] fp32 = CTX[32768 x 256](bf16) * Wo (as Wot[2048][256]).
// R11 structure: 128^2 tile, global_load_lds staging, LDS-bounce NT epilogue.
__global__ __launch_bounds__(256) void gemm_kern(
        const unsigned short* __restrict__ A,
        const unsigned short* __restrict__ Bt,
        float* __restrict__ C, int cpx) {
    __shared__ __align__(16) unsigned char smem[32768];
    unsigned short* Asl = (unsigned short*)smem;            // 16 KB, linear
    unsigned short* Bsl = (unsigned short*)(smem + 16384);  // 16 KB, linear
    const int bid = (int)blockIdx.x;
    const int logical = (bid & 7) * cpx + (bid >> 3);
    const int bx = logical & 15;
    const int by = logical >> 4;
    const int t = threadIdx.x, l = t & 63, w = t >> 6;
    const int li = l & 15, g = l >> 4;
    const int wr = w >> 1, wc = w & 1;
    const int rowA = by * 128, colB = bx * 128;
    f32x4 acc[4][4];
#pragma unroll
    for (int m = 0; m < 4; ++m)
#pragma unroll
        for (int n = 0; n < 4; ++n) acc[m][n] = (f32x4){0.f, 0.f, 0.f, 0.f};

    for (int kk = 0; kk < 4; ++kk) {
        // stage A/B tiles: 1024 chunks each; inverse-swizzled global source
#pragma unroll
        for (int j = 0; j < 4; ++j) {
            const int seg = j * 4 + w;              // 0..15
            const int chunk = seg * 64 + l;         // 0..1023
            const int row = chunk >> 3, c8 = chunk & 7;
            const int src8 = (c8 ^ (row & 7)) * 8;  // inverse swizzle on source
            gload16(&A[(size_t)(rowA + row) * 256 + kk * 64 + src8],
                    &Asl[seg * 512]);
            gload16(&Bt[(size_t)(colB + row) * 256 + kk * 64 + src8],
                    &Bsl[seg * 512]);
        }
        __syncthreads();
#pragma unroll
        for (int hh = 0; hh < 2; ++hh) {
            bf16x8 af[4], bfr[4];
#pragma unroll
            for (int m = 0; m < 4; ++m) {
                int row = wr * 64 + m * 16 + li;
                af[m] = *(const bf16x8*)&Asl[row * 64 + (((hh * 4 + g) ^ (row & 7)) * 8)];
            }
#pragma unroll
            for (int n = 0; n < 4; ++n) {
                int row = wc * 64 + n * 16 + li;
                bfr[n] = *(const bf16x8*)&Bsl[row * 64 + (((hh * 4 + g) ^ (row & 7)) * 8)];
            }
#pragma unroll
            for (int m = 0; m < 4; ++m)
#pragma unroll
                for (int n = 0; n < 4; ++n)
                    acc[m][n] = MFMA16(bfr[n], af[m], acc[m][n]);   // C^T frag
        }
        __syncthreads();
    }
    // epilogue: wave-private LDS bounce -> 256B-contiguous NT row stores
    float* osl = (float*)smem;
    const int wb = w * 1088;
#pragma unroll
    for (int m = 0; m < 4; ++m) {
#pragma unroll
        for (int n = 0; n < 4; ++n) {
            int c16 = (n * 4 + g) ^ (li & 3);
            *(f32x4*)&osl[wb + li * 68 + c16 * 4] = acc[m][n];
        }
#pragma unroll
        for (int r = 0; r < 4; ++r) {
            int chunk = r * 64 + l;
            int row = chunk >> 4, cic = chunk & 15;
            f32x4 v = *(const f32x4*)&osl[wb + row * 68 + (cic ^ (row & 3)) * 4];
            const int rr = rowA + wr * 64 + m * 16 + row;
            const int cc = colB + wc * 64 + cic * 4;
            __builtin_nontemporal_store(v, (f32x4*)&C[(size_t)rr * 2048 + cc]);
        }
    }
}

// ------------------------------- launch ------------------------------------
extern "C" void kernel_launch(void* const* d_in, const int* in_sizes, int n_in,
                              void* d_out, int out_size, void* d_ws, size_t ws_size,
                              hipStream_t stream) {
    (void)in_sizes; (void)n_in; (void)out_size; (void)ws_size;
    const float* queries = (const float*)d_in[0];
    const float* keys    = (const float*)d_in[1];
    const float* values  = (const float*)d_in[2];
    const int*   mask    = (const int*)d_in[3];
    const float* Wq = (const float*)d_in[4];
    const float* Wk = (const float*)d_in[5];
    const float* Wv = (const float*)d_in[6];
    const float* Wo = (const float*)d_in[7];

    unsigned short* CTX = (unsigned short*)d_ws;          // [32768][256] bf16
    unsigned short* Qbf = CTX + (size_t)32768 * 256;      // [3][4096][256] bf16
    unsigned short* Wt  = Qbf + (size_t)3 * 4096 * 256;   // [4][2048][256] bf16
    uint32_t* maskbits  = (uint32_t*)(Wt + (size_t)4 * 2048 * 256);  // [8][16][512]

    prep_kern<<<dim3(5376), 256, 0, stream>>>(queries, keys, values, mask,
                                              Wq, Wk, Wv, Wo,
                                              Qbf, Qbf + 4096 * 256, Qbf + 2 * 4096 * 256,
                                              Wt, maskbits);
    fused_kern<<<dim3(256), 1024, 0, stream>>>(Qbf, Qbf + 4096 * 256,
                                               Qbf + 2 * 4096 * 256,
                                               Wt, maskbits, CTX);
    gemm_kern<<<dim3(4096), 256, 0, stream>>>(CTX, Wt + (size_t)3 * 2048 * 256,
                                              (float*)d_out, 512);
}